// Round 3
// baseline (1304.208 us; speedup 1.0000x reference)
//
#include <hip/hip_runtime.h>

// QueryPinnedHopfieldLayer on MI355X (gfx950). ALL inputs/outputs are fp32
// (per harness contract: reference dtypes are float32). Internal K/V are bf16
// for the MFMA GEMM; z/tau/xi in fp32.
//
// Big scratch (K, V, z, mu, rs = 58.0 MB) lives inside d_out (134.2 MB fp32),
// which is fully overwritten by the final broadcast kernel. ~81 KB of small
// state (xi ping-pong, max keys, tau, beta, out row) lives in d_ws.
//
// Pipeline:
//   row_stats: per-row mean/rstd of memory_bank (50000 x 768 fp32)
//   qprep:     LN(query_embedding) @ Wq^T -> xi0 (8x4x64); beta = exp(log_beta)
//   gemm_kv:   MFMA bf16 GEMM  C = LN(mb) @ [Wk;Wv]^T  (M=50000, N=512, K=768),
//              LN + fp32->bf16 fused into A/B staging; K,V bf16 [head][row][64]
//   3x steps:  step_init -> scores_k (z = 0.5*beta*xi.K, per-(b,h) max via atomicMax key)
//              entmax_k (Newton root of sum((z-tau)+^2)=1, bracket [max-1, max];
//                        convex decreasing f, left-start => monotone, no overshoot)
//              xiupd_k  (xi' = sum w*V, w=(z-tau)+^2, skip all-zero groups of 8 rows)
//   finout:    out_row[b] = xi[b] @ Wo^T (8x2048 fp32) -> ws
//   bcast:     broadcast 8x2048 -> 8x2048x2048 fp32 over ALL of d_out (134 MB)

typedef unsigned short u16;
typedef unsigned int u32;

typedef __bf16 bf16x8 __attribute__((ext_vector_type(8)));
typedef float f32x4 __attribute__((ext_vector_type(4)));

#define GN 50000
#define NH 4
#define HD 64
#define NB 8
#define MD 768
#define HID 2048

__device__ __forceinline__ float bf2f(u16 u) {
  union { u32 i; float f; } v; v.i = ((u32)u) << 16; return v.f;
}
__device__ __forceinline__ u16 f2bf(float f) {
  u32 x = __float_as_uint(f);
  u32 r = (x + 0x7FFFu + ((x >> 16) & 1u)) >> 16;
  return (u16)r;
}
// order-preserving float->uint key for atomicMax
__device__ __forceinline__ u32 fkey(float f) {
  u32 u = __float_as_uint(f);
  return (u & 0x80000000u) ? ~u : (u | 0x80000000u);
}
__device__ __forceinline__ float kinv(u32 k) {
  u32 u = (k & 0x80000000u) ? (k & 0x7FFFFFFFu) : ~k;
  return __uint_as_float(u);
}

// ---- scratch layout inside d_out (bytes; all 16B aligned) ----
#define K_OFF   0ull
#define V_OFF   25600000ull      // 4*50000*64 bf16
#define Z_OFF   51200000ull      // 32*50000 f32
#define MU_OFF  57600000ull      // 50000 f32
#define RS_OFF  57800000ull      // ends 58.0 MB < 134.2 MB
// ---- small state in d_ws (bytes) ----
#define XIA_OFF   0u
#define XIB_OFF   8192u
#define MX_OFF    16384u
#define T_OFF     16640u
#define BETA_OFF  16896u
#define OUTS_OFF  17408u         // 8*2048 f32 = 65536 -> ends ~81 KB

// ---------------- kernels ----------------

__global__ __launch_bounds__(256) void row_stats(const float* __restrict__ mb,
                                                 float* __restrict__ mu, float* __restrict__ rs) {
  int row = blockIdx.x * 4 + (threadIdx.x >> 6);
  int lane = threadIdx.x & 63;
  if (row >= GN) return;
  const float4* p4 = (const float4*)(mb + (size_t)row * MD);
  float s = 0.f, ss = 0.f;
#pragma unroll
  for (int j = 0; j < 3; ++j) {
    float4 u = p4[lane + j * 64];
    s += u.x + u.y + u.z + u.w;
    ss += u.x * u.x + u.y * u.y + u.z * u.z + u.w * u.w;
  }
  for (int o = 32; o > 0; o >>= 1) { s += __shfl_down(s, o); ss += __shfl_down(ss, o); }
  if (lane == 0) {
    float m = s * (1.f / 768.f);
    float var = ss * (1.f / 768.f) - m * m;
    mu[row] = m;
    rs[row] = rsqrtf(fmaxf(var, 0.f) + 1e-5f);
  }
}

__global__ __launch_bounds__(256) void qprep(const float* __restrict__ qe, const float* __restrict__ Wq,
                                             const float* __restrict__ gq, const float* __restrict__ bq,
                                             const float* __restrict__ lb, float* __restrict__ xi0,
                                             float* __restrict__ beta) {
  int b = blockIdx.x, t = threadIdx.x;
  __shared__ float nq[768];
  __shared__ float w1[4], w2[4];
  float s = 0.f, ss = 0.f;
  for (int j = t; j < 768; j += 256) { float x = qe[b * 768 + j]; s += x; ss += x * x; }
  for (int o = 32; o > 0; o >>= 1) { s += __shfl_down(s, o); ss += __shfl_down(ss, o); }
  if ((t & 63) == 0) { w1[t >> 6] = s; w2[t >> 6] = ss; }
  __syncthreads();
  float S = w1[0] + w1[1] + w1[2] + w1[3];
  float SS = w2[0] + w2[1] + w2[2] + w2[3];
  float m = S * (1.f / 768.f);
  float var = SS * (1.f / 768.f) - m * m;
  float r = rsqrtf(fmaxf(var, 0.f) + 1e-5f);
  for (int j = t; j < 768; j += 256) {
    float x = qe[b * 768 + j];
    nq[j] = (x - m) * r * gq[j] + bq[j];
  }
  __syncthreads();
  const float4* wrow = (const float4*)(Wq + (size_t)t * 768);
  float acc = 0.f;
  for (int k = 0; k < 192; ++k) {
    float4 wv = wrow[k];
    acc += nq[k * 4] * wv.x + nq[k * 4 + 1] * wv.y + nq[k * 4 + 2] * wv.z + nq[k * 4 + 3] * wv.w;
  }
  xi0[b * 256 + t] = acc;
  if (b == 0 && t < 4) beta[t] = expf(lb[t]);
}

// C = LN(mb) @ W^T, 128x128 tile, BK=64, 4 waves (2x2 of 64x64), 16x16x32 bf16 MFMA
__global__ __launch_bounds__(256) void gemm_kv(const float* __restrict__ mb,
                                               const float* __restrict__ Wk, const float* __restrict__ Wv,
                                               const float* __restrict__ gm, const float* __restrict__ bm,
                                               const float* __restrict__ mu, const float* __restrict__ rs,
                                               u16* __restrict__ Kbuf, u16* __restrict__ Vbuf) {
  __shared__ u16 As[128][72];   // +8 pad, rows 144B (16B aligned)
  __shared__ u16 Bs[128][72];
  int t = threadIdx.x;
  int i0 = blockIdx.x * 128;
  int j0 = blockIdx.y * 128;
  const float* W = (j0 < 256) ? Wk : Wv;
  int jb = j0 & 255;
  u16* obuf = (j0 < 256) ? Kbuf : Vbuf;

  int w = t >> 6, lane = t & 63;
  int wm = w & 1, wn = w >> 1;
  int quad = lane >> 4, l16 = lane & 15;
  int seg = t & 7, r0 = t >> 3;

  f32x4 acc[4][4];
#pragma unroll
  for (int a = 0; a < 4; ++a)
#pragma unroll
    for (int b = 0; b < 4; ++b) { f32x4 zz = {0.f, 0.f, 0.f, 0.f}; acc[a][b] = zz; }

  for (int k0 = 0; k0 < 768; k0 += 64) {
    int kk8 = k0 + seg * 8;
    float4 g0 = *(const float4*)(gm + kk8);
    float4 g1 = *(const float4*)(gm + kk8 + 4);
    float4 b0 = *(const float4*)(bm + kk8);
    float4 b1 = *(const float4*)(bm + kk8 + 4);
    // stage A with fused LN (fp32 -> bf16)
#pragma unroll
    for (int rr = 0; rr < 4; ++rr) {
      int r = r0 + rr * 32;
      int row = i0 + r;
      u16 o8[8] __attribute__((aligned(16)));
      if (row < GN) {
        float4 a0 = *(const float4*)(mb + (size_t)row * MD + kk8);
        float4 a1 = *(const float4*)(mb + (size_t)row * MD + kk8 + 4);
        float mm = mu[row], ri = rs[row];
        o8[0] = f2bf((a0.x - mm) * ri * g0.x + b0.x);
        o8[1] = f2bf((a0.y - mm) * ri * g0.y + b0.y);
        o8[2] = f2bf((a0.z - mm) * ri * g0.z + b0.z);
        o8[3] = f2bf((a0.w - mm) * ri * g0.w + b0.w);
        o8[4] = f2bf((a1.x - mm) * ri * g1.x + b1.x);
        o8[5] = f2bf((a1.y - mm) * ri * g1.y + b1.y);
        o8[6] = f2bf((a1.z - mm) * ri * g1.z + b1.z);
        o8[7] = f2bf((a1.w - mm) * ri * g1.w + b1.w);
      } else {
#pragma unroll
        for (int e = 0; e < 8; ++e) o8[e] = 0;
      }
      *(uint4*)&As[r][seg * 8] = *(const uint4*)o8;
    }
    // stage B (fp32 -> bf16)
#pragma unroll
    for (int rr = 0; rr < 4; ++rr) {
      int n = r0 + rr * 32;
      float4 w0 = *(const float4*)(W + (size_t)(jb + n) * MD + kk8);
      float4 w1 = *(const float4*)(W + (size_t)(jb + n) * MD + kk8 + 4);
      u16 o8[8] __attribute__((aligned(16)));
      o8[0] = f2bf(w0.x); o8[1] = f2bf(w0.y); o8[2] = f2bf(w0.z); o8[3] = f2bf(w0.w);
      o8[4] = f2bf(w1.x); o8[5] = f2bf(w1.y); o8[6] = f2bf(w1.z); o8[7] = f2bf(w1.w);
      *(uint4*)&Bs[n][seg * 8] = *(const uint4*)o8;
    }
    __syncthreads();
#pragma unroll
    for (int kk = 0; kk < 64; kk += 32) {
      bf16x8 af[4], bfr[4];
#pragma unroll
      for (int tm = 0; tm < 4; ++tm)
        af[tm] = *(const bf16x8*)&As[wm * 64 + tm * 16 + l16][kk + quad * 8];
#pragma unroll
      for (int tn = 0; tn < 4; ++tn)
        bfr[tn] = *(const bf16x8*)&Bs[wn * 64 + tn * 16 + l16][kk + quad * 8];
#pragma unroll
      for (int tm = 0; tm < 4; ++tm)
#pragma unroll
        for (int tn = 0; tn < 4; ++tn)
          acc[tm][tn] = __builtin_amdgcn_mfma_f32_16x16x32_bf16(af[tm], bfr[tn], acc[tm][tn], 0, 0, 0);
    }
    __syncthreads();
  }
  // epilogue: D row = quad*4+reg, col = l16
#pragma unroll
  for (int tm = 0; tm < 4; ++tm) {
#pragma unroll
    for (int tn = 0; tn < 4; ++tn) {
      int jcol = j0 + wn * 64 + tn * 16 + l16;
      int hh = (jcol & 255) >> 6;
      int dd = jcol & 63;
#pragma unroll
      for (int rg = 0; rg < 4; ++rg) {
        int i = i0 + wm * 64 + tm * 16 + quad * 4 + rg;
        if (i < GN) obuf[((size_t)hh * GN + i) * HD + dd] = f2bf(acc[tm][tn][rg]);
      }
    }
  }
}

__global__ __launch_bounds__(256) void step_init(float* __restrict__ xi_new, u32* __restrict__ mxk) {
  int t = blockIdx.x * 256 + threadIdx.x;
  if (t < NB * NH * HD) xi_new[t] = 0.f;
  if (t < NB * NH) mxk[t] = 0u;
}

// z[b][h][i] = 0.5*beta[h]*sum_d xi[b,h,d]*K[h,i,d]; also per-(b,h) max key
__global__ __launch_bounds__(256) void scores_k(const u16* __restrict__ Kbuf, const float* __restrict__ xi,
                                                const float* __restrict__ beta, float* __restrict__ z,
                                                u32* __restrict__ mxk) {
  int h = blockIdx.y;
  int row0 = blockIdx.x * 64;
  int t = threadIdx.x;
  __shared__ u16 Ks[64][72];
  __shared__ float xis[8][64];
  {
    int f = t;
    xis[f >> 6][f & 63] = xi[(f >> 6) * 256 + h * 64 + (f & 63)];
    f = t + 256;
    xis[f >> 6][f & 63] = xi[(f >> 6) * 256 + h * 64 + (f & 63)];
  }
  {
    int r = t >> 3, d0 = (t & 7) * 8;
#pragma unroll
    for (int rr = 0; rr < 2; ++rr) {
      int ri = r + rr * 32;
      int row = row0 + ri;
      uint4 val = make_uint4(0, 0, 0, 0);
      if (row < GN) val = *(const uint4*)(Kbuf + ((size_t)h * GN + row) * HD + d0);
      *(uint4*)&Ks[ri][d0] = val;
    }
  }
  __syncthreads();
  int i = t & 63, bg = t >> 6;
  float a0 = 0.f, a1 = 0.f;
#pragma unroll
  for (int dd = 0; dd < 64; dd += 4) {
    ushort4 k4 = *(const ushort4*)&Ks[i][dd];
    float k0 = bf2f(k4.x), k1 = bf2f(k4.y), k2 = bf2f(k4.z), k3 = bf2f(k4.w);
    a0 += k0 * xis[bg][dd] + k1 * xis[bg][dd + 1] + k2 * xis[bg][dd + 2] + k3 * xis[bg][dd + 3];
    a1 += k0 * xis[bg + 4][dd] + k1 * xis[bg + 4][dd + 1] + k2 * xis[bg + 4][dd + 2] + k3 * xis[bg + 4][dd + 3];
  }
  float bh = beta[h];
  float z0 = 0.5f * bh * a0;
  float z1 = 0.5f * bh * a1;
  int row = row0 + i;
  if (row < GN) {
    z[((size_t)(bg * 4 + h)) * GN + row] = z0;
    z[((size_t)((bg + 4) * 4 + h)) * GN + row] = z1;
  } else {
    z0 = -1e30f; z1 = -1e30f;
  }
  for (int o = 32; o > 0; o >>= 1) {
    z0 = fmaxf(z0, __shfl_down(z0, o));
    z1 = fmaxf(z1, __shfl_down(z1, o));
  }
  if (i == 0) {
    atomicMax(&mxk[bg * 4 + h], fkey(z0));
    atomicMax(&mxk[(bg + 4) * 4 + h], fkey(z1));
  }
}

// Newton root of f(tau) = sum((z - tau)+^2) - 1, bracket [max-1, max]
__global__ __launch_bounds__(1024) void entmax_k(const float* __restrict__ z, const u32* __restrict__ mxk,
                                                 float* __restrict__ T) {
  int bh = blockIdx.x;
  const float* zp = z + (size_t)bh * GN;
  int t = threadIdx.x, w = t >> 6, lane = t & 63;
  __shared__ float rs1[16], rs2[16];
  __shared__ float tsh, dsh;
  float mx = kinv(mxk[bh]);
  float tau = mx - 1.f;
  for (int it = 0; it < 48; ++it) {
    float s1 = 0.f, s2 = 0.f;
    for (int i = t; i < GN; i += 1024) {
      float d = zp[i] - tau;
      d = fmaxf(d, 0.f);
      s1 += d; s2 += d * d;
    }
    for (int o = 32; o > 0; o >>= 1) { s1 += __shfl_down(s1, o); s2 += __shfl_down(s2, o); }
    if (lane == 0) { rs1[w] = s1; rs2[w] = s2; }
    __syncthreads();
    if (t == 0) {
      float S1 = 0.f, S2 = 0.f;
#pragma unroll
      for (int q = 0; q < 16; ++q) { S1 += rs1[q]; S2 += rs2[q]; }
      float dt = (S2 - 1.f) / (2.f * fmaxf(S1, 1e-12f));
      tau += dt;
      tsh = tau; dsh = dt;
    }
    __syncthreads();
    tau = tsh;
    if (fabsf(dsh) < 1e-7f) break;
  }
  if (t == 0) T[bh] = tau;
}

// xi_new[b,h,d] += sum_i ((z[b,h,i]-T)+)^2 * V[h,i,d]; groups of 8 rows, sparse skip
__global__ __launch_bounds__(512) void xiupd_k(const float* __restrict__ z, const float* __restrict__ T,
                                               const u16* __restrict__ Vbuf, float* __restrict__ xi_new) {
  int h = blockIdx.y;
  int row0 = blockIdx.x * 1024;
  int t = threadIdx.x;
  int b = t >> 6, d = t & 63;
  __shared__ float zs[8][1024];
#pragma unroll
  for (int j = 0; j < 16; ++j) {
    int f = t + j * 512;
    int bb = f >> 10, i = f & 1023;
    int row = row0 + i;
    zs[bb][i] = (row < GN) ? z[((size_t)(bb * 4 + h)) * GN + row] : -1e30f;
  }
  __syncthreads();
  float Tv = T[b * 4 + h];
  float acc = 0.f;
  for (int ii = 0; ii < 1024; ii += 8) {
    float wv[8];
#pragma unroll
    for (int e = 0; e < 8; ++e) wv[e] = zs[b][ii + e] - Tv;
    float m8 = wv[0];
#pragma unroll
    for (int e = 1; e < 8; ++e) m8 = fmaxf(m8, wv[e]);
    if (m8 <= 0.f) continue;
    const u16* vrow = Vbuf + ((size_t)h * GN + row0 + ii) * HD + d;
#pragma unroll
    for (int e = 0; e < 8; ++e) {
      float we = fmaxf(wv[e], 0.f);
      float v = bf2f(vrow[e * HD]);   // groups 8-aligned; 50000%8==0 so no mixed group
      acc += we * we * v;
    }
  }
  atomicAdd(&xi_new[b * 256 + h * 64 + d], acc);
}

// out_row[b][o] = sum_t xi[b][t] * Wo[o][t]; wave per (b,o); fp32 row in ws
__global__ __launch_bounds__(256) void finout_k(const float* __restrict__ xi, const float* __restrict__ Wo,
                                                float* __restrict__ outs) {
  int w = threadIdx.x >> 6, lane = threadIdx.x & 63;
  int flat = blockIdx.x * 4 + w;
  int b = flat >> 11, o = flat & 2047;
  const float4* wp = (const float4*)(Wo + (size_t)o * 256);
  const float4* xp = (const float4*)(xi + b * 256);
  float4 w4 = wp[lane];
  float4 x4 = xp[lane];
  float acc = w4.x * x4.x + w4.y * x4.y + w4.z * x4.z + w4.w * x4.w;
  for (int o2 = 32; o2 > 0; o2 >>= 1) acc += __shfl_down(acc, o2);
  if (lane == 0) outs[flat] = acc;
}

__global__ __launch_bounds__(256) void bcast_k(const float* __restrict__ outs, float* __restrict__ out) {
  int idx = blockIdx.x * 256 + threadIdx.x;   // float4 index; rows are 512 float4
  int row = idx >> 9, o = idx & 511;
  int b = row >> 11;
  ((float4*)out)[idx] = ((const float4*)outs)[b * 512 + o];
}

// ---------------- launch ----------------
extern "C" void kernel_launch(void* const* d_in, const int* in_sizes, int n_in,
                              void* d_out, int out_size, void* d_ws, size_t ws_size,
                              hipStream_t stream) {
  const float* qe = (const float*)d_in[1];
  const float* mb = (const float*)d_in[2];
  const float* Wq = (const float*)d_in[3];
  const float* Wk = (const float*)d_in[4];
  const float* Wv = (const float*)d_in[5];
  const float* Wo = (const float*)d_in[6];
  const float* lb = (const float*)d_in[7];
  const float* gq = (const float*)d_in[8];
  const float* bq = (const float*)d_in[9];
  const float* gm = (const float*)d_in[10];
  const float* bm = (const float*)d_in[11];

  char* ob = (char*)d_out;
  u16*   Kb   = (u16*)(ob + K_OFF);
  u16*   Vb   = (u16*)(ob + V_OFF);
  float* z    = (float*)(ob + Z_OFF);
  float* mu   = (float*)(ob + MU_OFF);
  float* rsb  = (float*)(ob + RS_OFF);

  char* ws = (char*)d_ws;
  float* xiA  = (float*)(ws + XIA_OFF);
  float* xiB  = (float*)(ws + XIB_OFF);
  u32*   mxk  = (u32*)(ws + MX_OFF);
  float* T    = (float*)(ws + T_OFF);
  float* beta = (float*)(ws + BETA_OFF);
  float* outs = (float*)(ws + OUTS_OFF);

  row_stats<<<12500, 256, 0, stream>>>(mb, mu, rsb);
  qprep<<<8, 256, 0, stream>>>(qe, Wq, gq, bq, lb, xiA, beta);
  gemm_kv<<<dim3(391, 4), 256, 0, stream>>>(mb, Wk, Wv, gm, bm, mu, rsb, Kb, Vb);

  float* xin = xiA;
  float* xout = xiB;
  for (int s = 0; s < 3; ++s) {
    step_init<<<8, 256, 0, stream>>>(xout, mxk);
    scores_k<<<dim3(782, 4), 256, 0, stream>>>(Kb, xin, beta, z, mxk);
    entmax_k<<<32, 1024, 0, stream>>>(z, mxk, T);
    xiupd_k<<<dim3(49, 4), 512, 0, stream>>>(z, T, Vb, xout);
    float* tmp = xin; xin = xout; xout = tmp;
  }

  finout_k<<<4096, 256, 0, stream>>>(xin, Wo, outs);
  bcast_k<<<32768, 256, 0, stream>>>(outs, (float*)d_out);
}

// Round 4
// 961.574 us; speedup vs baseline: 1.3563x; 1.3563x over previous
//
#include <hip/hip_runtime.h>

// QueryPinnedHopfieldLayer on MI355X (gfx950). fp32 in/out; internal K/V bf16.
// d_out (134.2 MB) doubles as scratch: ln_mb bf16 (76.8 MB, aliased by z after
// gemm), K (25.6), V (25.6), wkv bf16 (0.79), bmax (0.1). ws holds ~80 KB of
// small state (<= 82944 B proven available in round 3).
//
// Round-4 changes vs round 3 (which passed at 1304 us):
//  - scores_k: device atomicMax (serialization, 151us -> est 14us) replaced by
//    per-wave block-max stores; entmax reduces bmax.
//  - entmax_k: Newton with LDS support-compaction (tau monotone rising =>
//    survivors-only list after ~3 full scans); |dt|<1e-6 exit, 28 cap.
//    Also zeroes xi_out (replaces step_init).
//  - gemm: row_ln writes LN(mb) as bf16 once; wconv pre-converts Wk|Wv bf16;
//    gemm stages pure copies, BM=64 BN=256 (A re-read 4x->2x, no LN VALU).

typedef unsigned short u16;
typedef unsigned int u32;

typedef __bf16 bf16x8 __attribute__((ext_vector_type(8)));
typedef float f32x4 __attribute__((ext_vector_type(4)));

#define GN 50000
#define NH 4
#define HD 64
#define NB 8
#define MD 768
#define HID 2048
#define NBLK 782
#define LIST_CAP 12288

__device__ __forceinline__ float bf2f(u16 u) {
  union { u32 i; float f; } v; v.i = ((u32)u) << 16; return v.f;
}
__device__ __forceinline__ u16 f2bf(float f) {
  u32 x = __float_as_uint(f);
  u32 r = (x + 0x7FFFu + ((x >> 16) & 1u)) >> 16;
  return (u16)r;
}

// ---- scratch layout inside d_out (bytes; 16B aligned) ----
#define LN_OFF   0ull            // 50000*768 bf16 = 76.8 MB (dead after gemm)
#define Z_OFF    0ull            // 32*50000 f32 = 6.4 MB (aliases LN, written by scores)
#define K_OFF    76800000ull     // 4*50000*64 bf16
#define V_OFF    102400000ull
#define WKV_OFF  128000000ull    // 512*768 bf16
#define BMAX_OFF 128786432ull    // 32*782 f32 -> ends 128.9 MB < 134.2 MB
// ---- small state in d_ws ----
#define XIA_OFF   0u
#define XIB_OFF   8192u
#define T_OFF     16384u
#define BETA_OFF  16512u
#define OUTS_OFF  16640u         // 8*2048 f32 -> ends 82176 (< 82944 proven)

// ---------------- kernels ----------------

// LN(memory_bank) -> bf16, one wave per row (row held in registers)
__global__ __launch_bounds__(256) void row_ln(const float* __restrict__ mb,
                                              const float* __restrict__ gm,
                                              const float* __restrict__ bm,
                                              u16* __restrict__ ln) {
  int row = blockIdx.x * 4 + (threadIdx.x >> 6);
  int lane = threadIdx.x & 63;
  const float4* p4 = (const float4*)(mb + (size_t)row * MD);
  float4 v[3];
  float s = 0.f, ss = 0.f;
#pragma unroll
  for (int j = 0; j < 3; ++j) {
    v[j] = p4[lane + 64 * j];
    s += v[j].x + v[j].y + v[j].z + v[j].w;
    ss += v[j].x * v[j].x + v[j].y * v[j].y + v[j].z * v[j].z + v[j].w * v[j].w;
  }
  for (int o = 32; o > 0; o >>= 1) { s += __shfl_down(s, o); ss += __shfl_down(ss, o); }
  s = __shfl(s, 0); ss = __shfl(ss, 0);
  float m = s * (1.f / 768.f);
  float var = ss * (1.f / 768.f) - m * m;
  float r = rsqrtf(fmaxf(var, 0.f) + 1e-5f);
#pragma unroll
  for (int j = 0; j < 3; ++j) {
    float4 g = ((const float4*)gm)[lane + 64 * j];
    float4 b = ((const float4*)bm)[lane + 64 * j];
    ushort4 o4;
    o4.x = f2bf((v[j].x - m) * r * g.x + b.x);
    o4.y = f2bf((v[j].y - m) * r * g.y + b.y);
    o4.z = f2bf((v[j].z - m) * r * g.z + b.z);
    o4.w = f2bf((v[j].w - m) * r * g.w + b.w);
    *(ushort4*)(ln + (size_t)row * MD + (lane + 64 * j) * 4) = o4;
  }
}

// Wk|Wv fp32 -> bf16 (512x768 flat)
__global__ __launch_bounds__(256) void wconv(const float* __restrict__ Wk,
                                             const float* __restrict__ Wv,
                                             u16* __restrict__ wkv) {
  int i = blockIdx.x * 256 + threadIdx.x;   // float4 index, 98304 total
  float4 v = (i < 49152) ? ((const float4*)Wk)[i] : ((const float4*)Wv)[i - 49152];
  ushort4 o;
  o.x = f2bf(v.x); o.y = f2bf(v.y); o.z = f2bf(v.z); o.w = f2bf(v.w);
  ((ushort4*)wkv)[i] = o;
}

__global__ __launch_bounds__(256) void qprep(const float* __restrict__ qe, const float* __restrict__ Wq,
                                             const float* __restrict__ gq, const float* __restrict__ bq,
                                             const float* __restrict__ lb, float* __restrict__ xi0,
                                             float* __restrict__ beta) {
  int b = blockIdx.x, t = threadIdx.x;
  __shared__ float nq[768];
  __shared__ float w1[4], w2[4];
  float s = 0.f, ss = 0.f;
  for (int j = t; j < 768; j += 256) { float x = qe[b * 768 + j]; s += x; ss += x * x; }
  for (int o = 32; o > 0; o >>= 1) { s += __shfl_down(s, o); ss += __shfl_down(ss, o); }
  if ((t & 63) == 0) { w1[t >> 6] = s; w2[t >> 6] = ss; }
  __syncthreads();
  float S = w1[0] + w1[1] + w1[2] + w1[3];
  float SS = w2[0] + w2[1] + w2[2] + w2[3];
  float m = S * (1.f / 768.f);
  float var = SS * (1.f / 768.f) - m * m;
  float r = rsqrtf(fmaxf(var, 0.f) + 1e-5f);
  for (int j = t; j < 768; j += 256) {
    float x = qe[b * 768 + j];
    nq[j] = (x - m) * r * gq[j] + bq[j];
  }
  __syncthreads();
  const float4* wrow = (const float4*)(Wq + (size_t)t * 768);
  float acc = 0.f;
  for (int k = 0; k < 192; ++k) {
    float4 wv = wrow[k];
    acc += nq[k * 4] * wv.x + nq[k * 4 + 1] * wv.y + nq[k * 4 + 2] * wv.z + nq[k * 4 + 3] * wv.w;
  }
  xi0[b * 256 + t] = acc;
  if (b == 0 && t < 4) beta[t] = expf(lb[t]);
}

// C = ln_mb(bf16) @ wkv^T. BM=64, BN=256, BK=64; 4 waves each 64x64.
__global__ __launch_bounds__(256) void gemm_kv(const u16* __restrict__ ln,
                                               const u16* __restrict__ wkv,
                                               u16* __restrict__ Kbuf, u16* __restrict__ Vbuf) {
  __shared__ u16 As[64][72];
  __shared__ u16 Bs[256][72];
  int t = threadIdx.x;
  int i0 = blockIdx.x * 64;
  int j0 = blockIdx.y;          // 0 -> K, 1 -> V
  int jb = j0 * 256;
  u16* obuf = j0 ? Vbuf : Kbuf;

  int w = t >> 6, lane = t & 63;
  int quad = lane >> 4, l16 = lane & 15;

  f32x4 acc[4][4];
#pragma unroll
  for (int a = 0; a < 4; ++a)
#pragma unroll
    for (int b = 0; b < 4; ++b) { f32x4 zz = {0.f, 0.f, 0.f, 0.f}; acc[a][b] = zz; }

  for (int k0 = 0; k0 < 768; k0 += 64) {
    // stage A: 64x64 bf16, 512 16B chunks
#pragma unroll
    for (int cc = 0; cc < 2; ++cc) {
      int c = t + cc * 256;
      int r = c >> 3, seg = c & 7;
      int row = i0 + r;
      uint4 val = make_uint4(0, 0, 0, 0);
      if (row < GN) val = *(const uint4*)(ln + (size_t)row * MD + k0 + seg * 8);
      *(uint4*)&As[r][seg * 8] = val;
    }
    // stage B: 256x64 bf16, 2048 chunks
#pragma unroll
    for (int cc = 0; cc < 8; ++cc) {
      int c = t + cc * 256;
      int n = c >> 3, seg = c & 7;
      *(uint4*)&Bs[n][seg * 8] = *(const uint4*)(wkv + (size_t)(jb + n) * MD + k0 + seg * 8);
    }
    __syncthreads();
#pragma unroll
    for (int kk = 0; kk < 64; kk += 32) {
      bf16x8 af[4], bfr[4];
#pragma unroll
      for (int tm = 0; tm < 4; ++tm)
        af[tm] = *(const bf16x8*)&As[tm * 16 + l16][kk + quad * 8];
#pragma unroll
      for (int tn = 0; tn < 4; ++tn)
        bfr[tn] = *(const bf16x8*)&Bs[w * 64 + tn * 16 + l16][kk + quad * 8];
#pragma unroll
      for (int tm = 0; tm < 4; ++tm)
#pragma unroll
        for (int tn = 0; tn < 4; ++tn)
          acc[tm][tn] = __builtin_amdgcn_mfma_f32_16x16x32_bf16(af[tm], bfr[tn], acc[tm][tn], 0, 0, 0);
    }
    __syncthreads();
  }
  // epilogue: D row = quad*4+reg (M), col = l16 (N)
#pragma unroll
  for (int tm = 0; tm < 4; ++tm) {
#pragma unroll
    for (int tn = 0; tn < 4; ++tn) {
      int lc = w * 64 + tn * 16 + l16;      // 0..255
      int hh = lc >> 6;
      int dd = lc & 63;
#pragma unroll
      for (int rg = 0; rg < 4; ++rg) {
        int i = i0 + tm * 16 + quad * 4 + rg;
        if (i < GN) obuf[((size_t)hh * GN + i) * HD + dd] = f2bf(acc[tm][tn][rg]);
      }
    }
  }
}

// z[bh][i] = 0.5*beta[h]*xi[b,h,:].K[h,i,:]; per-wave block max -> bmax (no atomics)
__global__ __launch_bounds__(256) void scores_k(const u16* __restrict__ Kbuf, const float* __restrict__ xi,
                                                const float* __restrict__ beta, float* __restrict__ z,
                                                float* __restrict__ bmax) {
  int h = blockIdx.y;
  int row0 = blockIdx.x * 64;
  int t = threadIdx.x;
  __shared__ u16 Ks[64][72];
  __shared__ float xis[8][64];
  {
    int f = t;
    xis[f >> 6][f & 63] = xi[(f >> 6) * 256 + h * 64 + (f & 63)];
    f = t + 256;
    xis[f >> 6][f & 63] = xi[(f >> 6) * 256 + h * 64 + (f & 63)];
  }
  {
    int r = t >> 3, d0 = (t & 7) * 8;
#pragma unroll
    for (int rr = 0; rr < 2; ++rr) {
      int ri = r + rr * 32;
      int row = row0 + ri;
      uint4 val = make_uint4(0, 0, 0, 0);
      if (row < GN) val = *(const uint4*)(Kbuf + ((size_t)h * GN + row) * HD + d0);
      *(uint4*)&Ks[ri][d0] = val;
    }
  }
  __syncthreads();
  int i = t & 63, bg = t >> 6;
  float a0 = 0.f, a1 = 0.f;
#pragma unroll
  for (int dd = 0; dd < 64; dd += 4) {
    ushort4 k4 = *(const ushort4*)&Ks[i][dd];
    float4 x0 = *(const float4*)&xis[bg][dd];
    float4 x1 = *(const float4*)&xis[bg + 4][dd];
    float k0 = bf2f(k4.x), k1 = bf2f(k4.y), k2 = bf2f(k4.z), k3 = bf2f(k4.w);
    a0 += k0 * x0.x + k1 * x0.y + k2 * x0.z + k3 * x0.w;
    a1 += k0 * x1.x + k1 * x1.y + k2 * x1.z + k3 * x1.w;
  }
  float bh = beta[h];
  float z0 = 0.5f * bh * a0;
  float z1 = 0.5f * bh * a1;
  int row = row0 + i;
  if (row < GN) {
    z[((size_t)(bg * 4 + h)) * GN + row] = z0;
    z[((size_t)((bg + 4) * 4 + h)) * GN + row] = z1;
  } else {
    z0 = -1e30f; z1 = -1e30f;
  }
  for (int o = 32; o > 0; o >>= 1) {
    z0 = fmaxf(z0, __shfl_down(z0, o));
    z1 = fmaxf(z1, __shfl_down(z1, o));
  }
  if (i == 0) {
    bmax[(size_t)(bg * 4 + h) * NBLK + blockIdx.x] = z0;
    bmax[(size_t)((bg + 4) * 4 + h) * NBLK + blockIdx.x] = z1;
  }
}

// Newton root of sum((z-tau)+^2)=1 with LDS support compaction; zeroes xi_out
__global__ __launch_bounds__(1024) void entmax_k(const float* __restrict__ z,
                                                 const float* __restrict__ bmax,
                                                 float* __restrict__ T, float* __restrict__ xout) {
  int bh = blockIdx.x;
  const float* zp = z + (size_t)bh * GN;
  int t = threadIdx.x, w = t >> 6, lane = t & 63;
  __shared__ float rs1[16], rs2[16];
  __shared__ float tsh, dsh;
  __shared__ int lcount, cflag;
  __shared__ float list[LIST_CAP];
  if (t == 0) { lcount = 0; cflag = 0; }
  float m = -1e30f;
  for (int i = t; i < NBLK; i += 1024) m = fmaxf(m, bmax[(size_t)bh * NBLK + i]);
  for (int o = 32; o > 0; o >>= 1) m = fmaxf(m, __shfl_down(m, o));
  if (lane == 0) rs1[w] = m;
  __syncthreads();
  if (t == 0) {
    float mx = rs1[0];
#pragma unroll
    for (int q = 1; q < 16; ++q) mx = fmaxf(mx, rs1[q]);
    tsh = mx - 1.f;
  }
  __syncthreads();
  float tau = tsh;
  for (int it = 0; it < 28; ++it) {
    float s1 = 0.f, s2 = 0.f;
    if (cflag) {
      int n = lcount;
      for (int i = t; i < n; i += 1024) {
        float d = fmaxf(list[i] - tau, 0.f);
        s1 += d; s2 += d * d;
      }
    } else {
      bool tryc = (it >= 2);
      for (int i = t; i < GN; i += 1024) {
        float zv = zp[i];
        float d = zv - tau;
        float dp = fmaxf(d, 0.f);
        s1 += dp; s2 += dp * dp;
        if (tryc) {
          bool keep = d > 0.f;
          unsigned long long mk = __ballot(keep);
          if (mk) {
            int leader = __ffsll(mk) - 1;
            int base = 0;
            if (lane == leader) base = atomicAdd(&lcount, (int)__popcll(mk));
            base = __shfl(base, leader);
            if (keep) {
              int pos = base + (int)__popcll(mk & ((1ull << lane) - 1ull));
              if (pos < LIST_CAP) list[pos] = zv;
            }
          }
        }
      }
    }
    for (int o = 32; o > 0; o >>= 1) { s1 += __shfl_down(s1, o); s2 += __shfl_down(s2, o); }
    if (lane == 0) { rs1[w] = s1; rs2[w] = s2; }
    __syncthreads();
    if (t == 0) {
      float S1 = 0.f, S2 = 0.f;
#pragma unroll
      for (int q = 0; q < 16; ++q) { S1 += rs1[q]; S2 += rs2[q]; }
      float dt = (S2 - 1.f) / (2.f * fmaxf(S1, 1e-12f));
      tsh = tau + dt; dsh = dt;
      if (!cflag && it >= 2) {
        if (lcount <= LIST_CAP) cflag = 1; else lcount = 0;
      }
    }
    __syncthreads();
    tau = tsh;
    if (fabsf(dsh) < 1e-6f) break;
  }
  if (t == 0) T[bh] = tau;
  if (t < 64) xout[bh * 64 + t] = 0.f;
}

// xi_new[b,h,d] += sum_i ((z-T)+)^2 * V[h,i,d]; skip all-zero groups of 8 rows
__global__ __launch_bounds__(512) void xiupd_k(const float* __restrict__ z, const float* __restrict__ T,
                                               const u16* __restrict__ Vbuf, float* __restrict__ xi_new) {
  int h = blockIdx.y;
  int row0 = blockIdx.x * 1024;
  int t = threadIdx.x;
  int b = t >> 6, d = t & 63;
  __shared__ float zs[8][1024];
#pragma unroll
  for (int j = 0; j < 16; ++j) {
    int f = t + j * 512;
    int bb = f >> 10, i = f & 1023;
    int row = row0 + i;
    zs[bb][i] = (row < GN) ? z[((size_t)(bb * 4 + h)) * GN + row] : -1e30f;
  }
  __syncthreads();
  float Tv = T[b * 4 + h];
  float acc = 0.f;
  for (int ii = 0; ii < 1024; ii += 8) {
    float wv[8];
#pragma unroll
    for (int e = 0; e < 8; ++e) wv[e] = zs[b][ii + e] - Tv;
    float m8 = wv[0];
#pragma unroll
    for (int e = 1; e < 8; ++e) m8 = fmaxf(m8, wv[e]);
    if (m8 <= 0.f) continue;
    const u16* vrow = Vbuf + ((size_t)h * GN + row0 + ii) * HD + d;
#pragma unroll
    for (int e = 0; e < 8; ++e) {
      float we = fmaxf(wv[e], 0.f);
      float v = bf2f(vrow[e * HD]);
      acc += we * we * v;
    }
  }
  atomicAdd(&xi_new[b * 256 + h * 64 + d], acc);
}

__global__ __launch_bounds__(256) void finout_k(const float* __restrict__ xi, const float* __restrict__ Wo,
                                                float* __restrict__ outs) {
  int w = threadIdx.x >> 6, lane = threadIdx.x & 63;
  int flat = blockIdx.x * 4 + w;
  int b = flat >> 11, o = flat & 2047;
  const float4* wp = (const float4*)(Wo + (size_t)o * 256);
  const float4* xp = (const float4*)(xi + b * 256);
  float4 w4 = wp[lane];
  float4 x4 = xp[lane];
  float acc = w4.x * x4.x + w4.y * x4.y + w4.z * x4.z + w4.w * x4.w;
  for (int o2 = 32; o2 > 0; o2 >>= 1) acc += __shfl_down(acc, o2);
  if (lane == 0) outs[flat] = acc;
}

__global__ __launch_bounds__(256) void bcast_k(const float* __restrict__ outs, float* __restrict__ out) {
  int idx = blockIdx.x * 256 + threadIdx.x;   // float4 index; rows are 512 float4
  int row = idx >> 9, o = idx & 511;
  int b = row >> 11;
  ((float4*)out)[idx] = ((const float4*)outs)[b * 512 + o];
}

// ---------------- launch ----------------
extern "C" void kernel_launch(void* const* d_in, const int* in_sizes, int n_in,
                              void* d_out, int out_size, void* d_ws, size_t ws_size,
                              hipStream_t stream) {
  const float* qe = (const float*)d_in[1];
  const float* mb = (const float*)d_in[2];
  const float* Wq = (const float*)d_in[3];
  const float* Wk = (const float*)d_in[4];
  const float* Wv = (const float*)d_in[5];
  const float* Wo = (const float*)d_in[6];
  const float* lb = (const float*)d_in[7];
  const float* gq = (const float*)d_in[8];
  const float* bq = (const float*)d_in[9];
  const float* gm = (const float*)d_in[10];
  const float* bm = (const float*)d_in[11];

  char* ob = (char*)d_out;
  u16*   ln   = (u16*)(ob + LN_OFF);
  float* z    = (float*)(ob + Z_OFF);
  u16*   Kb   = (u16*)(ob + K_OFF);
  u16*   Vb   = (u16*)(ob + V_OFF);
  u16*   wkv  = (u16*)(ob + WKV_OFF);
  float* bmax = (float*)(ob + BMAX_OFF);

  char* ws = (char*)d_ws;
  float* xiA  = (float*)(ws + XIA_OFF);
  float* xiB  = (float*)(ws + XIB_OFF);
  float* T    = (float*)(ws + T_OFF);
  float* beta = (float*)(ws + BETA_OFF);
  float* outs = (float*)(ws + OUTS_OFF);

  row_ln<<<12500, 256, 0, stream>>>(mb, gm, bm, ln);
  wconv<<<384, 256, 0, stream>>>(Wk, Wv, wkv);
  qprep<<<8, 256, 0, stream>>>(qe, Wq, gq, bq, lb, xiA, beta);
  gemm_kv<<<dim3(782, 2), 256, 0, stream>>>(ln, wkv, Kb, Vb);

  float* xin = xiA;
  float* xout = xiB;
  for (int s = 0; s < 3; ++s) {
    scores_k<<<dim3(782, 4), 256, 0, stream>>>(Kb, xin, beta, z, bmax);
    entmax_k<<<32, 1024, 0, stream>>>(z, bmax, T, xout);
    xiupd_k<<<dim3(49, 4), 512, 0, stream>>>(z, T, Vb, xout);
    float* tmp = xin; xin = xout; xout = tmp;
  }

  finout_k<<<4096, 256, 0, stream>>>(xin, Wo, outs);
  bcast_k<<<32768, 256, 0, stream>>>(outs, (float*)d_out);
}